// Round 1
// baseline (1156.664 us; speedup 1.0000x reference)
//
#include <hip/hip_runtime.h>

#define NN 100000
#define NE 800000
#define IND 64
#define HID 96
#define NL 3
#define NC 512
#define BN_EPS 1e-5f

// ---------------- embedding: h = relu(x @ W_emb + b_emb) ----------------
// 512 threads, 128-node chunk, per-thread 4x6 register tile, K=64
__global__ __launch_bounds__(512) void k_embed(const float* __restrict__ x,
        const float* __restrict__ W, const float* __restrict__ b,
        float* __restrict__ h) {
    __shared__ float sW[IND * HID];     // 24 KB
    __shared__ float sb[HID];
    __shared__ float rows[128 * 65];    // 33.3 KB (pad 65 -> group stride %32 = 4)
    const int tid = threadIdx.x;
    for (int i = tid; i < IND * HID; i += 512) sW[i] = W[i];
    if (tid < HID) sb[tid] = b[tid];
    const int node0 = blockIdx.x * 128;
    for (int i = tid; i < 128 * IND; i += 512) {
        int n = i >> 6, k = i & 63;
        int g = node0 + n;
        rows[n * 65 + k] = (g < NN) ? x[(long)g * IND + k] : 0.f;
    }
    __syncthreads();
    const int tj = tid & 15;
    const int nb = (tid >> 4) * 4;
    float acc[4][6];
#pragma unroll
    for (int a = 0; a < 4; ++a)
#pragma unroll
        for (int c = 0; c < 6; ++c) acc[a][c] = 0.f;
    for (int k = 0; k < IND; ++k) {
        float w0 = sW[k*HID + tj],      w1 = sW[k*HID + tj + 16];
        float w2 = sW[k*HID + tj + 32], w3 = sW[k*HID + tj + 48];
        float w4 = sW[k*HID + tj + 64], w5 = sW[k*HID + tj + 80];
#pragma unroll
        for (int a = 0; a < 4; ++a) {
            float r = rows[(nb + a) * 65 + k];
            acc[a][0] += r * w0; acc[a][1] += r * w1; acc[a][2] += r * w2;
            acc[a][3] += r * w3; acc[a][4] += r * w4; acc[a][5] += r * w5;
        }
    }
#pragma unroll
    for (int a = 0; a < 4; ++a) {
        int g = node0 + nb + a;
        if (g < NN) {
#pragma unroll
            for (int c = 0; c < 6; ++c) {
                int j = tj + 16 * c;
                float v = acc[a][c] + sb[j];
                h[(long)g * HID + j] = v > 0.f ? v : 0.f;
            }
        }
    }
}

// ---------------- CSR build ----------------
__global__ void k_hist(const int* __restrict__ ei, int* __restrict__ hist) {
    int e = blockIdx.x * blockDim.x + threadIdx.x;
    if (e < NE) atomicAdd(&hist[ei[NE + e]], 1);
}

__global__ __launch_bounds__(1024) void k_scan(const int* __restrict__ hist,
                                               int* __restrict__ rp) {
    __shared__ int part[1024];
    const int tid = threadIdx.x;
    const int CH = (NN + 1023) / 1024;   // 98
    const int base = tid * CH;
    int s = 0;
    for (int i = 0; i < CH; ++i) {
        int n = base + i;
        if (n < NN) s += hist[n];
    }
    part[tid] = s;
    __syncthreads();
    for (int off = 1; off < 1024; off <<= 1) {
        int v = (tid >= off) ? part[tid - off] : 0;
        __syncthreads();
        part[tid] += v;
        __syncthreads();
    }
    int run = part[tid] - s;   // exclusive prefix of this chunk
    for (int i = 0; i < CH; ++i) {
        int n = base + i;
        if (n < NN) { rp[n] = run; run += hist[n]; }
    }
    if (tid == 1023) rp[NN] = part[1023];
}

__global__ void k_fill(const int* __restrict__ ei, int* __restrict__ cursor,
                       int* __restrict__ col) {
    int e = blockIdx.x * blockDim.x + threadIdx.x;
    if (e < NE) {
        int d = ei[NE + e];
        int pos = atomicAdd(&cursor[d], 1);
        col[pos] = ei[e];
    }
}

// ---------------- mean aggregation (CSR gather) ----------------
// 32 lanes per node, 8 nodes per 256-thread block
__global__ __launch_bounds__(256) void k_agg(const float* __restrict__ h,
        const int* __restrict__ rp, const int* __restrict__ col,
        float* __restrict__ agg) {
    const int lane = threadIdx.x & 31;
    const int grp  = threadIdx.x >> 5;
    const int n = blockIdx.x * 8 + grp;
    if (n >= NN) return;
    const int e0 = rp[n], e1 = rp[n + 1];
    float a0 = 0.f, a1 = 0.f, a2 = 0.f;
    for (int e = e0; e < e1; ++e) {
        const float* hr = h + (long)col[e] * HID;
        a0 += hr[lane]; a1 += hr[lane + 32]; a2 += hr[lane + 64];
    }
    int d = e1 - e0; if (d < 1) d = 1;
    float inv = 1.0f / (float)d;
    float* ar = agg + (long)n * HID;
    ar[lane] = a0 * inv; ar[lane + 32] = a1 * inv; ar[lane + 64] = a2 * inv;
}

// ---------------- layer GEMM: hnew = agg@wl + bl + h@wr ----------------
// 512 threads, 128-node chunk, two K=96 passes sharing one row buffer
__global__ __launch_bounds__(512) void k_gemm(const float* __restrict__ agg,
        const float* __restrict__ h, const float* __restrict__ wl,
        const float* __restrict__ wr, const float* __restrict__ bl,
        float* __restrict__ hnew) {
    __shared__ float sW[2 * HID * HID];   // 72 KB
    __shared__ float rows[128 * 97];      // 49.7 KB
    const int tid = threadIdx.x;
    for (int i = tid; i < HID * HID; i += 512) {
        sW[i] = wl[i];
        sW[HID * HID + i] = wr[i];
    }
    const int node0 = blockIdx.x * 128;
    for (int i = tid; i < 128 * HID; i += 512) {
        int n = i / 96, k = i % 96;
        int g = node0 + n;
        rows[n * 97 + k] = (g < NN) ? agg[(long)g * HID + k] : 0.f;
    }
    __syncthreads();
    const int tj = tid & 15;
    const int nb = (tid >> 4) * 4;
    float acc[4][6];
#pragma unroll
    for (int a = 0; a < 4; ++a)
#pragma unroll
        for (int c = 0; c < 6; ++c) acc[a][c] = 0.f;
    for (int k = 0; k < HID; ++k) {
        float w0 = sW[k*HID + tj],      w1 = sW[k*HID + tj + 16];
        float w2 = sW[k*HID + tj + 32], w3 = sW[k*HID + tj + 48];
        float w4 = sW[k*HID + tj + 64], w5 = sW[k*HID + tj + 80];
#pragma unroll
        for (int a = 0; a < 4; ++a) {
            float r = rows[(nb + a) * 97 + k];
            acc[a][0] += r * w0; acc[a][1] += r * w1; acc[a][2] += r * w2;
            acc[a][3] += r * w3; acc[a][4] += r * w4; acc[a][5] += r * w5;
        }
    }
    __syncthreads();
    for (int i = tid; i < 128 * HID; i += 512) {
        int n = i / 96, k = i % 96;
        int g = node0 + n;
        rows[n * 97 + k] = (g < NN) ? h[(long)g * HID + k] : 0.f;
    }
    __syncthreads();
    for (int k = 0; k < HID; ++k) {
        const float* w = sW + HID * HID;
        float w0 = w[k*HID + tj],      w1 = w[k*HID + tj + 16];
        float w2 = w[k*HID + tj + 32], w3 = w[k*HID + tj + 48];
        float w4 = w[k*HID + tj + 64], w5 = w[k*HID + tj + 80];
#pragma unroll
        for (int a = 0; a < 4; ++a) {
            float r = rows[(nb + a) * 97 + k];
            acc[a][0] += r * w0; acc[a][1] += r * w1; acc[a][2] += r * w2;
            acc[a][3] += r * w3; acc[a][4] += r * w4; acc[a][5] += r * w5;
        }
    }
#pragma unroll
    for (int a = 0; a < 4; ++a) {
        int g = node0 + nb + a;
        if (g < NN) {
#pragma unroll
            for (int c = 0; c < 6; ++c) {
                int j = tj + 16 * c;
                hnew[(long)g * HID + j] = acc[a][c] + bl[j];
            }
        }
    }
}

// ---------------- BN column stats ----------------
__global__ __launch_bounds__(192) void k_stats(const float* __restrict__ hnew,
                                               float* __restrict__ stats) {
    const int tid = threadIdx.x;
    const int j = tid % 96;
    const int r = tid / 96;            // 0..1
    const int ROWS = 512;
    const int n0 = blockIdx.x * ROWS;
    const int nend = (n0 + ROWS < NN) ? n0 + ROWS : NN;
    float s = 0.f, ss = 0.f;
    for (int n = n0 + r; n < nend; n += 2) {
        float v = hnew[(long)n * 96 + j];
        s += v; ss += v * v;
    }
    __shared__ float ls[192], lss[192];
    ls[tid] = s; lss[tid] = ss;
    __syncthreads();
    if (r == 0) {
        atomicAdd(&stats[j],      ls[tid] + ls[tid + 96]);
        atomicAdd(&stats[96 + j], lss[tid] + lss[tid + 96]);
    }
}

// ---------------- BN normalize + relu ----------------
__global__ __launch_bounds__(256) void k_norm(const float* __restrict__ hnew,
        const float* __restrict__ stats, const float* __restrict__ gamma,
        const float* __restrict__ beta, float* __restrict__ h) {
    __shared__ float sc[96], sh[96];
    const int tid = threadIdx.x;
    if (tid < 96) {
        float mean = stats[tid] * (1.0f / NN);
        float var  = stats[96 + tid] * (1.0f / NN) - mean * mean;
        float s = gamma[tid] * rsqrtf(var + BN_EPS);
        sc[tid] = s;
        sh[tid] = beta[tid] - mean * s;
    }
    __syncthreads();
    const int total4 = NN * 96 / 4;
    for (int i = blockIdx.x * blockDim.x + tid; i < total4; i += gridDim.x * blockDim.x) {
        float4 v = ((const float4*)hnew)[i];
        int j0 = (i * 4) % 96;
        float4 o;
        o.x = fmaxf(v.x * sc[j0]     + sh[j0],     0.f);
        o.y = fmaxf(v.y * sc[j0 + 1] + sh[j0 + 1], 0.f);
        o.z = fmaxf(v.z * sc[j0 + 2] + sh[j0 + 2], 0.f);
        o.w = fmaxf(v.w * sc[j0 + 3] + sh[j0 + 3], 0.f);
        ((float4*)h)[i] = o;
    }
}

// ---------------- central-node MLP head ----------------
__global__ __launch_bounds__(128) void k_mlp(const float* __restrict__ h,
        const int* __restrict__ cidx, const float* __restrict__ W1,
        const float* __restrict__ b1, const float* __restrict__ W2,
        const float* __restrict__ b2, float* __restrict__ out) {
    __shared__ float hid[96];
    __shared__ float red[128];
    const int c = blockIdx.x;
    const int node = cidx[c];
    const int tid = threadIdx.x;
    if (tid < 96) {
        float a = 0.f;
        const float* hr = h + (long)node * 96;
        for (int k = 0; k < 96; ++k) a += hr[k] * W1[k * 96 + tid];
        hid[tid] = fmaxf(a + b1[tid], 0.f);
    }
    __syncthreads();
    red[tid] = (tid < 96) ? hid[tid] * W2[tid] : 0.f;
    __syncthreads();
    for (int off = 64; off > 0; off >>= 1) {
        if (tid < off) red[tid] += red[tid + off];
        __syncthreads();
    }
    if (tid == 0) out[c] = red[0] + b2[0];
}

extern "C" void kernel_launch(void* const* d_in, const int* in_sizes, int n_in,
                              void* d_out, int out_size, void* d_ws, size_t ws_size,
                              hipStream_t stream) {
    const float* x        = (const float*)d_in[0];
    const int*   ei       = (const int*)d_in[1];
    const int*   cidx     = (const int*)d_in[3];
    const float* W_emb    = (const float*)d_in[4];
    const float* b_emb    = (const float*)d_in[5];
    const float* conv_wl  = (const float*)d_in[6];
    const float* conv_bl  = (const float*)d_in[7];
    const float* conv_wr  = (const float*)d_in[8];
    const float* bn_gamma = (const float*)d_in[9];
    const float* bn_beta  = (const float*)d_in[10];
    const float* W1       = (const float*)d_in[11];
    const float* b1       = (const float*)d_in[12];
    const float* W2       = (const float*)d_in[13];
    const float* b2       = (const float*)d_in[14];
    float* out = (float*)d_out;

    char* ws = (char*)d_ws;
    size_t off = 0;
    auto alloc = [&](size_t bytes) -> void* {
        void* p = ws + off;
        off = (off + bytes + 255) & ~(size_t)255;
        return p;
    };
    float* h    = (float*)alloc((size_t)NN * 96 * 4);
    float* agg  = (float*)alloc((size_t)NN * 96 * 4);
    float* hnew = (float*)alloc((size_t)NN * 96 * 4);
    int*   hist = (int*)alloc((size_t)NN * 4);
    int*   rp   = (int*)alloc((size_t)(NN + 1) * 4);
    int*   curs = (int*)alloc((size_t)NN * 4);
    int*   col  = (int*)alloc((size_t)NE * 4);
    float* stats= (float*)alloc(2 * 96 * 4);
    (void)ws_size; (void)in_sizes; (void)n_in; (void)out_size;

    hipMemsetAsync(hist, 0, (size_t)NN * 4, stream);
    k_embed<<<(NN + 127) / 128, 512, 0, stream>>>(x, W_emb, b_emb, h);
    k_hist<<<(NE + 255) / 256, 256, 0, stream>>>(ei, hist);
    k_scan<<<1, 1024, 0, stream>>>(hist, rp);
    hipMemcpyAsync(curs, rp, (size_t)NN * 4, hipMemcpyDeviceToDevice, stream);
    k_fill<<<(NE + 255) / 256, 256, 0, stream>>>(ei, curs, col);

    for (int l = 0; l < NL; ++l) {
        k_agg<<<(NN + 7) / 8, 256, 0, stream>>>(h, rp, col, agg);
        k_gemm<<<(NN + 127) / 128, 512, 0, stream>>>(
            agg, h, conv_wl + (size_t)l * 96 * 96, conv_wr + (size_t)l * 96 * 96,
            conv_bl + (size_t)l * 96, hnew);
        hipMemsetAsync(stats, 0, 2 * 96 * 4, stream);
        k_stats<<<(NN + 511) / 512, 192, 0, stream>>>(hnew, stats);
        k_norm<<<2048, 256, 0, stream>>>(hnew, stats,
            bn_gamma + (size_t)l * 96, bn_beta + (size_t)l * 96, h);
    }
    k_mlp<<<NC, 128, 0, stream>>>(h, cidx, W1, b1, W2, b2, out);
}

// Round 2
// 694.520 us; speedup vs baseline: 1.6654x; 1.6654x over previous
//
#include <hip/hip_runtime.h>

#define NN 100000
#define NE 800000
#define IND 64
#define HID 96
#define NL 3
#define NC 512
#define BN_EPS 1e-5f

// ---------------- embedding: h = relu(x @ W_emb + b_emb) ----------------
// 512 threads, 128-node chunk, transposed-W LDS, float4 LDS reads, 4x6 reg tile
#define EPK 68   // padded K stride for embed (64 + 4)
__global__ __launch_bounds__(512) void k_embed(const float* __restrict__ x,
        const float* __restrict__ W, const float* __restrict__ b,
        float* __restrict__ h) {
    __shared__ float sWT[HID * EPK];    // 26.1 KB, sWT[j*EPK + k] = W[k*96 + j]
    __shared__ float rows[128 * EPK];   // 34.8 KB
    __shared__ float sb[HID];
    const int tid = threadIdx.x;
    for (int i = tid; i < IND * 24; i += 512) {     // 24 float4 per k-row
        int k = i / 24, j4 = (i % 24) * 4;
        float4 w = *(const float4*)&W[k * HID + j4];
        sWT[(j4 + 0) * EPK + k] = w.x;
        sWT[(j4 + 1) * EPK + k] = w.y;
        sWT[(j4 + 2) * EPK + k] = w.z;
        sWT[(j4 + 3) * EPK + k] = w.w;
    }
    if (tid < HID) sb[tid] = b[tid];
    const int node0 = blockIdx.x * 128;
    for (int i = tid; i < 128 * 16; i += 512) {     // 16 float4 per row (K=64)
        int n = i >> 4, k4 = (i & 15) * 4;
        int g = node0 + n;
        float4 v = (g < NN) ? *(const float4*)&x[(long)g * IND + k4]
                            : make_float4(0.f, 0.f, 0.f, 0.f);
        *(float4*)&rows[n * EPK + k4] = v;
    }
    __syncthreads();
    const int tj = tid & 15;
    const int nb = (tid >> 4) * 4;
    float acc[4][6];
#pragma unroll
    for (int a = 0; a < 4; ++a)
#pragma unroll
        for (int c = 0; c < 6; ++c) acc[a][c] = 0.f;
    for (int kk = 0; kk < IND; kk += 4) {
        float4 w4[6];
#pragma unroll
        for (int c = 0; c < 6; ++c)
            w4[c] = *(const float4*)&sWT[(tj + 16 * c) * EPK + kk];
#pragma unroll
        for (int a = 0; a < 4; ++a) {
            float4 r = *(const float4*)&rows[(nb + a) * EPK + kk];
#pragma unroll
            for (int c = 0; c < 6; ++c)
                acc[a][c] += r.x * w4[c].x + r.y * w4[c].y
                           + r.z * w4[c].z + r.w * w4[c].w;
        }
    }
#pragma unroll
    for (int a = 0; a < 4; ++a) {
        int g = node0 + nb + a;
        if (g < NN) {
#pragma unroll
            for (int c = 0; c < 6; ++c) {
                int j = tj + 16 * c;
                float v = acc[a][c] + sb[j];
                h[(long)g * HID + j] = v > 0.f ? v : 0.f;
            }
        }
    }
}

// ---------------- CSR build ----------------
__global__ void k_hist(const int* __restrict__ ei, int* __restrict__ hist) {
    int e = blockIdx.x * blockDim.x + threadIdx.x;
    if (e < NE) atomicAdd(&hist[ei[NE + e]], 1);
}

// hierarchical scan: 98 blocks x 1024
__global__ __launch_bounds__(1024) void k_scan1(const int* __restrict__ hist,
        int* __restrict__ rp, int* __restrict__ bsum) {
    __shared__ int sd[1024];
    const int tid = threadIdx.x;
    const int i = blockIdx.x * 1024 + tid;
    int v = (i < NN) ? hist[i] : 0;
    sd[tid] = v;
    __syncthreads();
    for (int off = 1; off < 1024; off <<= 1) {
        int t = (tid >= off) ? sd[tid - off] : 0;
        __syncthreads();
        sd[tid] += t;
        __syncthreads();
    }
    if (i < NN) rp[i] = sd[tid] - v;              // block-local exclusive
    if (tid == 1023) bsum[blockIdx.x] = sd[1023];
}

__global__ __launch_bounds__(128) void k_scan2(const int* __restrict__ bsum,
                                               int* __restrict__ boff) {
    __shared__ int sd[128];
    const int tid = threadIdx.x;
    const int NB = (NN + 1023) / 1024;   // 98
    int v = (tid < NB) ? bsum[tid] : 0;
    sd[tid] = v;
    __syncthreads();
    for (int off = 1; off < 128; off <<= 1) {
        int t = (tid >= off) ? sd[tid - off] : 0;
        __syncthreads();
        sd[tid] += t;
        __syncthreads();
    }
    if (tid < NB) boff[tid] = sd[tid] - v;        // exclusive
}

__global__ __launch_bounds__(1024) void k_scan3(int* __restrict__ rp,
        const int* __restrict__ boff) {
    const int i = blockIdx.x * 1024 + threadIdx.x;
    if (i < NN) rp[i] += boff[blockIdx.x];
    if (i == 0) rp[NN] = NE;
}

__global__ void k_fill(const int* __restrict__ ei, int* __restrict__ cursor,
                       int* __restrict__ col) {
    int e = blockIdx.x * blockDim.x + threadIdx.x;
    if (e < NE) {
        int d = ei[NE + e];
        int pos = atomicAdd(&cursor[d], 1);
        col[pos] = ei[e];
    }
}

// ---------------- mean aggregation (CSR gather) ----------------
__global__ __launch_bounds__(256) void k_agg(const float* __restrict__ h,
        const int* __restrict__ rp, const int* __restrict__ col,
        float* __restrict__ agg) {
    const int lane = threadIdx.x & 31;
    const int grp  = threadIdx.x >> 5;
    const int n = blockIdx.x * 8 + grp;
    if (n >= NN) return;
    const int e0 = rp[n], e1 = rp[n + 1];
    float a0 = 0.f, a1 = 0.f, a2 = 0.f;
    for (int e = e0; e < e1; ++e) {
        const float* hr = h + (long)col[e] * HID;
        a0 += hr[lane]; a1 += hr[lane + 32]; a2 += hr[lane + 64];
    }
    int d = e1 - e0; if (d < 1) d = 1;
    float inv = 1.0f / (float)d;
    float* ar = agg + (long)n * HID;
    ar[lane] = a0 * inv; ar[lane + 32] = a1 * inv; ar[lane + 64] = a2 * inv;
}

// ---------------- layer GEMM: hnew = agg@wl + bl + h@wr, fused BN stats ----
#define GPK 100  // padded K stride (96 + 4)
__global__ __launch_bounds__(512) void k_gemm(const float* __restrict__ agg,
        const float* __restrict__ h, const float* __restrict__ wl,
        const float* __restrict__ wr, const float* __restrict__ bl,
        float* __restrict__ hnew, float* __restrict__ stats) {
    __shared__ float sWT[2 * HID * GPK];  // 76.8 KB, [j*GPK+k]
    __shared__ float rows[128 * GPK];     // 51.2 KB
    const int tid = threadIdx.x;
    for (int i = tid; i < HID * 24; i += 512) {
        int k = i / 24, j4 = (i % 24) * 4;
        float4 a = *(const float4*)&wl[k * HID + j4];
        float4 b = *(const float4*)&wr[k * HID + j4];
        sWT[(j4 + 0) * GPK + k] = a.x; sWT[(j4 + 1) * GPK + k] = a.y;
        sWT[(j4 + 2) * GPK + k] = a.z; sWT[(j4 + 3) * GPK + k] = a.w;
        float* t = sWT + HID * GPK;
        t[(j4 + 0) * GPK + k] = b.x; t[(j4 + 1) * GPK + k] = b.y;
        t[(j4 + 2) * GPK + k] = b.z; t[(j4 + 3) * GPK + k] = b.w;
    }
    const int node0 = blockIdx.x * 128;
    for (int i = tid; i < 128 * 24; i += 512) {
        int n = i / 24, k4 = (i % 24) * 4;
        int g = node0 + n;
        float4 v = (g < NN) ? *(const float4*)&agg[(long)g * HID + k4]
                            : make_float4(0.f, 0.f, 0.f, 0.f);
        *(float4*)&rows[n * GPK + k4] = v;
    }
    __syncthreads();
    const int tj = tid & 15;
    const int nb = (tid >> 4) * 4;
    float acc[4][6];
#pragma unroll
    for (int a = 0; a < 4; ++a)
#pragma unroll
        for (int c = 0; c < 6; ++c) acc[a][c] = 0.f;
    const float* Wp = sWT;
    for (int pass = 0; pass < 2; ++pass) {
        for (int kk = 0; kk < HID; kk += 4) {
            float4 w4[6];
#pragma unroll
            for (int c = 0; c < 6; ++c)
                w4[c] = *(const float4*)&Wp[(tj + 16 * c) * GPK + kk];
#pragma unroll
            for (int a = 0; a < 4; ++a) {
                float4 r = *(const float4*)&rows[(nb + a) * GPK + kk];
#pragma unroll
                for (int c = 0; c < 6; ++c)
                    acc[a][c] += r.x * w4[c].x + r.y * w4[c].y
                               + r.z * w4[c].z + r.w * w4[c].w;
            }
        }
        if (pass == 0) {
            __syncthreads();
            for (int i = tid; i < 128 * 24; i += 512) {
                int n = i / 24, k4 = (i % 24) * 4;
                int g = node0 + n;
                float4 v = (g < NN) ? *(const float4*)&h[(long)g * HID + k4]
                                    : make_float4(0.f, 0.f, 0.f, 0.f);
                *(float4*)&rows[n * GPK + k4] = v;
            }
            __syncthreads();
            Wp = sWT + HID * GPK;
        }
    }
    // epilogue: bias, store, per-column partial stats
    float ps[6], pss[6];
#pragma unroll
    for (int c = 0; c < 6; ++c) { ps[c] = 0.f; pss[c] = 0.f; }
#pragma unroll
    for (int a = 0; a < 4; ++a) {
        int g = node0 + nb + a;
        if (g < NN) {
#pragma unroll
            for (int c = 0; c < 6; ++c) {
                int j = tj + 16 * c;
                float v = acc[a][c] + bl[j];
                hnew[(long)g * HID + j] = v;
                ps[c] += v; pss[c] += v * v;
            }
        }
    }
    // reduce across the 4 16-lane groups of each wave
#pragma unroll
    for (int c = 0; c < 6; ++c) {
        ps[c]  += __shfl_xor(ps[c], 16);  ps[c]  += __shfl_xor(ps[c], 32);
        pss[c] += __shfl_xor(pss[c], 16); pss[c] += __shfl_xor(pss[c], 32);
    }
    __syncthreads();                 // rows no longer needed; reuse as scratch
    float* ls = rows;                // [8][96] sums then [8][96] sumsq
    const int wv = tid >> 6, lane = tid & 63;
    if (lane < 16) {
#pragma unroll
        for (int c = 0; c < 6; ++c) {
            ls[wv * 96 + lane + 16 * c] = ps[c];
            ls[768 + wv * 96 + lane + 16 * c] = pss[c];
        }
    }
    __syncthreads();
    if (tid < 96) {
        float s = 0.f, ss = 0.f;
#pragma unroll
        for (int w = 0; w < 8; ++w) { s += ls[w * 96 + tid]; ss += ls[768 + w * 96 + tid]; }
        atomicAdd(&stats[tid], s);
        atomicAdd(&stats[96 + tid], ss);
    }
}

// ---------------- BN normalize + relu ----------------
__global__ __launch_bounds__(256) void k_norm(const float* __restrict__ hnew,
        const float* __restrict__ stats, const float* __restrict__ gamma,
        const float* __restrict__ beta, float* __restrict__ h) {
    __shared__ float sc[96], sh[96];
    const int tid = threadIdx.x;
    if (tid < 96) {
        float mean = stats[tid] * (1.0f / NN);
        float var  = stats[96 + tid] * (1.0f / NN) - mean * mean;
        float s = gamma[tid] * rsqrtf(var + BN_EPS);
        sc[tid] = s;
        sh[tid] = beta[tid] - mean * s;
    }
    __syncthreads();
    const int total4 = NN * 96 / 4;
    for (int i = blockIdx.x * blockDim.x + tid; i < total4; i += gridDim.x * blockDim.x) {
        float4 v = ((const float4*)hnew)[i];
        int j0 = (i * 4) % 96;
        float4 o;
        o.x = fmaxf(v.x * sc[j0]     + sh[j0],     0.f);
        o.y = fmaxf(v.y * sc[j0 + 1] + sh[j0 + 1], 0.f);
        o.z = fmaxf(v.z * sc[j0 + 2] + sh[j0 + 2], 0.f);
        o.w = fmaxf(v.w * sc[j0 + 3] + sh[j0 + 3], 0.f);
        ((float4*)h)[i] = o;
    }
}

// ---------------- central-node MLP head ----------------
__global__ __launch_bounds__(128) void k_mlp(const float* __restrict__ h,
        const int* __restrict__ cidx, const float* __restrict__ W1,
        const float* __restrict__ b1, const float* __restrict__ W2,
        const float* __restrict__ b2, float* __restrict__ out) {
    __shared__ float hid[96];
    __shared__ float red[128];
    const int c = blockIdx.x;
    const int node = cidx[c];
    const int tid = threadIdx.x;
    if (tid < 96) {
        float a = 0.f;
        const float* hr = h + (long)node * 96;
        for (int k = 0; k < 96; ++k) a += hr[k] * W1[k * 96 + tid];
        hid[tid] = fmaxf(a + b1[tid], 0.f);
    }
    __syncthreads();
    red[tid] = (tid < 96) ? hid[tid] * W2[tid] : 0.f;
    __syncthreads();
    for (int off = 64; off > 0; off >>= 1) {
        if (tid < off) red[tid] += red[tid + off];
        __syncthreads();
    }
    if (tid == 0) out[c] = red[0] + b2[0];
}

extern "C" void kernel_launch(void* const* d_in, const int* in_sizes, int n_in,
                              void* d_out, int out_size, void* d_ws, size_t ws_size,
                              hipStream_t stream) {
    const float* x        = (const float*)d_in[0];
    const int*   ei       = (const int*)d_in[1];
    const int*   cidx     = (const int*)d_in[3];
    const float* W_emb    = (const float*)d_in[4];
    const float* b_emb    = (const float*)d_in[5];
    const float* conv_wl  = (const float*)d_in[6];
    const float* conv_bl  = (const float*)d_in[7];
    const float* conv_wr  = (const float*)d_in[8];
    const float* bn_gamma = (const float*)d_in[9];
    const float* bn_beta  = (const float*)d_in[10];
    const float* W1       = (const float*)d_in[11];
    const float* b1       = (const float*)d_in[12];
    const float* W2       = (const float*)d_in[13];
    const float* b2       = (const float*)d_in[14];
    float* out = (float*)d_out;

    char* ws = (char*)d_ws;
    size_t off = 0;
    auto alloc = [&](size_t bytes) -> void* {
        void* p = ws + off;
        off = (off + bytes + 255) & ~(size_t)255;
        return p;
    };
    float* h    = (float*)alloc((size_t)NN * 96 * 4);
    float* agg  = (float*)alloc((size_t)NN * 96 * 4);
    float* hnew = (float*)alloc((size_t)NN * 96 * 4);
    int*   hist = (int*)alloc((size_t)NN * 4);
    int*   rp   = (int*)alloc((size_t)(NN + 1) * 4);
    int*   curs = (int*)alloc((size_t)NN * 4);
    int*   col  = (int*)alloc((size_t)NE * 4);
    int*   bsum = (int*)alloc(128 * 4);
    int*   boff = (int*)alloc(128 * 4);
    float* stats= (float*)alloc((size_t)NL * 192 * 4);
    (void)ws_size; (void)in_sizes; (void)n_in; (void)out_size;

    const int NB = (NN + 1023) / 1024;   // 98

    hipMemsetAsync(hist, 0, (size_t)NN * 4, stream);
    hipMemsetAsync(stats, 0, (size_t)NL * 192 * 4, stream);
    k_embed<<<(NN + 127) / 128, 512, 0, stream>>>(x, W_emb, b_emb, h);
    k_hist<<<(NE + 255) / 256, 256, 0, stream>>>(ei, hist);
    k_scan1<<<NB, 1024, 0, stream>>>(hist, rp, bsum);
    k_scan2<<<1, 128, 0, stream>>>(bsum, boff);
    k_scan3<<<NB, 1024, 0, stream>>>(rp, boff);
    hipMemcpyAsync(curs, rp, (size_t)NN * 4, hipMemcpyDeviceToDevice, stream);
    k_fill<<<(NE + 255) / 256, 256, 0, stream>>>(ei, curs, col);

    for (int l = 0; l < NL; ++l) {
        k_agg<<<(NN + 7) / 8, 256, 0, stream>>>(h, rp, col, agg);
        k_gemm<<<(NN + 127) / 128, 512, 0, stream>>>(
            agg, h, conv_wl + (size_t)l * 96 * 96, conv_wr + (size_t)l * 96 * 96,
            conv_bl + (size_t)l * 96, hnew, stats + (size_t)l * 192);
        k_norm<<<2048, 256, 0, stream>>>(hnew, stats + (size_t)l * 192,
            bn_gamma + (size_t)l * 96, bn_beta + (size_t)l * 96, h);
    }
    k_mlp<<<NC, 128, 0, stream>>>(h, cidx, W1, b1, W2, b2, out);
}

// Round 3
// 363.945 us; speedup vs baseline: 3.1781x; 1.9083x over previous
//
#include <hip/hip_runtime.h>

#define NN 100000
#define NE 800000
#define IND 64
#define HID 96
#define NL 3
#define NC 512
#define BN_EPS 1e-5f

typedef __attribute__((ext_vector_type(8))) short bf16x8;
typedef __attribute__((ext_vector_type(4))) float f32x4;

static __device__ __forceinline__ float b2f(ushort u) {
    union { uint i; float f; } v; v.i = ((uint)u) << 16; return v.f;
}
static __device__ __forceinline__ ushort f2b(float f) {
    union { float f; uint i; } v; v.f = f;
    uint r = v.i + 0x7FFFu + ((v.i >> 16) & 1u);
    return (ushort)(r >> 16);
}
static __device__ __forceinline__ uint pack2(float a, float b) {
    return (uint)f2b(a) | ((uint)f2b(b) << 16);
}

// ---- weight prep: fp32 [K][96] (srcA rows 0..95, srcB rows 96..191) ->
// frag-ordered bf16: dst[((kt*6+ct)*64+lane)*8+j] = W[kt*32+(lane>>4)*8+j][ct*16+(lane&15)]
__global__ void k_prep(const float* __restrict__ srcA, const float* __restrict__ srcB,
                       ushort* __restrict__ dst, int ktiles) {
    int t = blockIdx.x * blockDim.x + threadIdx.x;
    int total = ktiles * 6 * 64;
    if (t >= total) return;
    int lane = t & 63;
    int ct = (t >> 6) % 6;
    int kt = t / (6 * 64);
    int k0 = kt * 32 + (lane >> 4) * 8;
    int col = ct * 16 + (lane & 15);
    ushort tmp[8];
#pragma unroll
    for (int j = 0; j < 8; ++j) {
        int k = k0 + j;
        const float* src = (srcB == nullptr || k < 96) ? srcA : srcB;
        int kk = (srcB == nullptr || k < 96) ? k : k - 96;
        tmp[j] = f2b(src[kk * HID + col]);
    }
    uint* od = (uint*)(dst + (size_t)t * 8);
    od[0] = (uint)tmp[0] | ((uint)tmp[1] << 16);
    od[1] = (uint)tmp[2] | ((uint)tmp[3] << 16);
    od[2] = (uint)tmp[4] | ((uint)tmp[5] << 16);
    od[3] = (uint)tmp[6] | ((uint)tmp[7] << 16);
}

// ---- embedding: h = relu(x @ W_emb + b_emb), bf16 out, MFMA ----
__global__ __launch_bounds__(256, 4) void k_embed(const float* __restrict__ x,
        const ushort* __restrict__ Bf, const float* __restrict__ bias,
        ushort* __restrict__ h) {
    __shared__ __align__(16) char smem[24576];
    ushort* sB = (ushort*)smem;          // 2*6*64*8 = 6144 ushorts (12288 B)
    ushort* sT = (ushort*)smem;          // reused after sync: 128*96 (24576 B)
    const int tid = threadIdx.x;
    for (int i = tid; i < 768; i += 256) ((uint4*)sB)[i] = ((const uint4*)Bf)[i];
    __syncthreads();
    const int wave = tid >> 6, lane = tid & 63;
    const int rowb = wave * 32;
    const int row0 = blockIdx.x * 128 + rowb;
    const int kof = (lane >> 4) * 8;
    f32x4 acc[2][6];
#pragma unroll
    for (int t = 0; t < 2; ++t)
#pragma unroll
        for (int c = 0; c < 6; ++c) acc[t][c] = (f32x4){0.f, 0.f, 0.f, 0.f};
#pragma unroll
    for (int kt = 0; kt < 2; ++kt) {
        int kk = kt * 32 + kof;
        bf16x8 a[2];
#pragma unroll
        for (int t = 0; t < 2; ++t) {
            int r = row0 + t * 16 + (lane & 15);
            if (r >= NN) r = NN - 1;
            const float* src = x + (size_t)r * IND + kk;
            float4 f0 = *(const float4*)src;
            float4 f1 = *(const float4*)(src + 4);
            a[t][0] = (short)f2b(f0.x); a[t][1] = (short)f2b(f0.y);
            a[t][2] = (short)f2b(f0.z); a[t][3] = (short)f2b(f0.w);
            a[t][4] = (short)f2b(f1.x); a[t][5] = (short)f2b(f1.y);
            a[t][6] = (short)f2b(f1.z); a[t][7] = (short)f2b(f1.w);
        }
#pragma unroll
        for (int ct = 0; ct < 6; ++ct) {
            bf16x8 bb = *(const bf16x8*)&sB[((kt * 6 + ct) * 64 + lane) * 8];
            acc[0][ct] = __builtin_amdgcn_mfma_f32_16x16x32_bf16(a[0], bb, acc[0][ct], 0, 0, 0);
            acc[1][ct] = __builtin_amdgcn_mfma_f32_16x16x32_bf16(a[1], bb, acc[1][ct], 0, 0, 0);
        }
    }
    __syncthreads();   // done reading sB
#pragma unroll
    for (int t = 0; t < 2; ++t)
#pragma unroll
        for (int ct = 0; ct < 6; ++ct) {
            int col = ct * 16 + (lane & 15);
            float bv = bias[col];
#pragma unroll
            for (int i = 0; i < 4; ++i) {
                int rb = rowb + t * 16 + (lane >> 4) * 4 + i;
                float v = acc[t][ct][i] + bv;
                sT[rb * HID + col] = f2b(v > 0.f ? v : 0.f);
            }
        }
    __syncthreads();
    for (int i = tid; i < 1536; i += 256) {      // 128 rows * 12 uint4
        int r = i / 12;
        int g = blockIdx.x * 128 + r;
        if (g < NN) ((uint4*)(h + (size_t)g * HID))[i % 12] = ((uint4*)sT)[i];
    }
}

// ---------------- CSR build ----------------
__global__ void k_hist(const int* __restrict__ ei, int* __restrict__ hist) {
    int e = blockIdx.x * blockDim.x + threadIdx.x;
    if (e < NE) atomicAdd(&hist[ei[NE + e]], 1);
}

__global__ __launch_bounds__(1024) void k_scan1(const int* __restrict__ hist,
        int* __restrict__ rp, int* __restrict__ bsum) {
    __shared__ int sd[1024];
    const int tid = threadIdx.x;
    const int i = blockIdx.x * 1024 + tid;
    int v = (i < NN) ? hist[i] : 0;
    sd[tid] = v;
    __syncthreads();
    for (int off = 1; off < 1024; off <<= 1) {
        int t = (tid >= off) ? sd[tid - off] : 0;
        __syncthreads();
        sd[tid] += t;
        __syncthreads();
    }
    if (i < NN) rp[i] = sd[tid] - v;
    if (tid == 1023) bsum[blockIdx.x] = sd[1023];
}

__global__ __launch_bounds__(128) void k_scan2(const int* __restrict__ bsum,
                                               int* __restrict__ boff) {
    __shared__ int sd[128];
    const int tid = threadIdx.x;
    const int NB = (NN + 1023) / 1024;
    int v = (tid < NB) ? bsum[tid] : 0;
    sd[tid] = v;
    __syncthreads();
    for (int off = 1; off < 128; off <<= 1) {
        int t = (tid >= off) ? sd[tid - off] : 0;
        __syncthreads();
        sd[tid] += t;
        __syncthreads();
    }
    if (tid < NB) boff[tid] = sd[tid] - v;
}

__global__ __launch_bounds__(1024) void k_scan3(int* __restrict__ rp,
        const int* __restrict__ boff) {
    const int i = blockIdx.x * 1024 + threadIdx.x;
    if (i < NN) rp[i] += boff[blockIdx.x];
    if (i == 0) rp[NN] = NE;
}

__global__ void k_fill(const int* __restrict__ ei, int* __restrict__ cursor,
                       int* __restrict__ col) {
    int e = blockIdx.x * blockDim.x + threadIdx.x;
    if (e < NE) {
        int d = ei[NE + e];
        int pos = atomicAdd(&cursor[d], 1);
        col[pos] = ei[e];
    }
}

// ---------------- mean aggregation: 16 lanes/node, bf16 in/out, fp32 acc ----
__global__ __launch_bounds__(256) void k_agg(const ushort* __restrict__ h,
        const int* __restrict__ rp, const int* __restrict__ col,
        ushort* __restrict__ agg) {
    const int lane = threadIdx.x & 15;
    const int n = blockIdx.x * 16 + (threadIdx.x >> 4);
    if (n >= NN) return;
    const int e0 = rp[n], e1 = rp[n + 1];
    float a0 = 0.f, a1 = 0.f, a2 = 0.f, a3 = 0.f, a4 = 0.f, a5 = 0.f;
    const uint* hu = (const uint*)h;
    for (int e = e0; e < e1; ++e) {
        const uint* r = hu + (size_t)col[e] * 48 + lane;
        uint u0 = r[0], u1 = r[16], u2 = r[32];
        a0 += b2f((ushort)u0); a1 += b2f((ushort)(u0 >> 16));
        a2 += b2f((ushort)u1); a3 += b2f((ushort)(u1 >> 16));
        a4 += b2f((ushort)u2); a5 += b2f((ushort)(u2 >> 16));
    }
    int d = e1 - e0; if (d < 1) d = 1;
    float inv = 1.0f / (float)d;
    uint* ar = (uint*)agg + (size_t)n * 48 + lane;
    ar[0]  = pack2(a0 * inv, a1 * inv);
    ar[16] = pack2(a2 * inv, a3 * inv);
    ar[32] = pack2(a4 * inv, a5 * inv);
}

// ---- layer GEMM: hnew = [agg|h] @ [[wl],[wr]] + bl, fused BN stats, MFMA ----
__global__ __launch_bounds__(256, 4) void k_gemm(const ushort* __restrict__ agg,
        const ushort* __restrict__ h, const ushort* __restrict__ Bf,
        const float* __restrict__ bl, ushort* __restrict__ hnew,
        float* __restrict__ stats) {
    __shared__ __align__(16) char smem[39936];
    ushort* sB = (ushort*)smem;                    // 6*6*64*8 = 18432 ushorts (36864 B)
    ushort* sT = (ushort*)smem;                    // reused after sync (24576 B)
    float* sredS = (float*)(smem + 36864);         // 4*96
    float* sredQ = sredS + 384;                    // 4*96  (total 39936 B)
    const int tid = threadIdx.x;
    for (int i = tid; i < 2304; i += 256) ((uint4*)sB)[i] = ((const uint4*)Bf)[i];
    __syncthreads();
    const int wave = tid >> 6, lane = tid & 63;
    const int rowb = wave * 32;
    const int row0 = blockIdx.x * 128 + rowb;
    const int kof = (lane >> 4) * 8;
    f32x4 acc[2][6];
#pragma unroll
    for (int t = 0; t < 2; ++t)
#pragma unroll
        for (int c = 0; c < 6; ++c) acc[t][c] = (f32x4){0.f, 0.f, 0.f, 0.f};
#pragma unroll
    for (int kt = 0; kt < 6; ++kt) {
        const ushort* asrc = (kt < 3) ? agg : h;
        int kk = (kt < 3 ? kt : kt - 3) * 32 + kof;
        bf16x8 a[2];
#pragma unroll
        for (int t = 0; t < 2; ++t) {
            int r = row0 + t * 16 + (lane & 15);
            if (r >= NN) r = NN - 1;
            a[t] = *(const bf16x8*)(asrc + (size_t)r * HID + kk);
        }
#pragma unroll
        for (int ct = 0; ct < 6; ++ct) {
            bf16x8 bb = *(const bf16x8*)&sB[((kt * 6 + ct) * 64 + lane) * 8];
            acc[0][ct] = __builtin_amdgcn_mfma_f32_16x16x32_bf16(a[0], bb, acc[0][ct], 0, 0, 0);
            acc[1][ct] = __builtin_amdgcn_mfma_f32_16x16x32_bf16(a[1], bb, acc[1][ct], 0, 0, 0);
        }
    }
    __syncthreads();   // done reading sB
    float s[6], q[6];
#pragma unroll
    for (int c = 0; c < 6; ++c) { s[c] = 0.f; q[c] = 0.f; }
#pragma unroll
    for (int t = 0; t < 2; ++t)
#pragma unroll
        for (int ct = 0; ct < 6; ++ct) {
            int col = ct * 16 + (lane & 15);
            float bv = bl[col];
#pragma unroll
            for (int i = 0; i < 4; ++i) {
                int rb = rowb + t * 16 + (lane >> 4) * 4 + i;
                int g = blockIdx.x * 128 + rb;
                float v = acc[t][ct][i] + bv;
                if (g < NN) { s[ct] += v; q[ct] += v * v; }
                sT[rb * HID + col] = f2b(v);
            }
        }
#pragma unroll
    for (int c = 0; c < 6; ++c) {
        s[c] += __shfl_xor(s[c], 16); s[c] += __shfl_xor(s[c], 32);
        q[c] += __shfl_xor(q[c], 16); q[c] += __shfl_xor(q[c], 32);
    }
    if (lane < 16) {
#pragma unroll
        for (int c = 0; c < 6; ++c) {
            sredS[wave * 96 + c * 16 + lane] = s[c];
            sredQ[wave * 96 + c * 16 + lane] = q[c];
        }
    }
    __syncthreads();
    if (tid < 96) {
        float S = sredS[tid] + sredS[96 + tid] + sredS[192 + tid] + sredS[288 + tid];
        float Q = sredQ[tid] + sredQ[96 + tid] + sredQ[192 + tid] + sredQ[288 + tid];
        atomicAdd(&stats[tid], S);
        atomicAdd(&stats[96 + tid], Q);
    }
    for (int i = tid; i < 1536; i += 256) {
        int r = i / 12;
        int g = blockIdx.x * 128 + r;
        if (g < NN) ((uint4*)(hnew + (size_t)g * HID))[i % 12] = ((uint4*)sT)[i];
    }
}

// ---------------- BN normalize + relu (bf16 in/out) ----------------
__global__ __launch_bounds__(256) void k_norm(const ushort* __restrict__ hnew,
        const float* __restrict__ stats, const float* __restrict__ gamma,
        const float* __restrict__ beta, ushort* __restrict__ h) {
    __shared__ float sc[96], sh[96];
    const int tid = threadIdx.x;
    if (tid < 96) {
        float mean = stats[tid] * (1.0f / NN);
        float var  = stats[96 + tid] * (1.0f / NN) - mean * mean;
        float sv = gamma[tid] * rsqrtf(var + BN_EPS);
        sc[tid] = sv;
        sh[tid] = beta[tid] - mean * sv;
    }
    __syncthreads();
    const int total4 = NN * 48 / 4;     // uint4 count (8 bf16 each)
    for (int i = blockIdx.x * blockDim.x + tid; i < total4; i += gridDim.x * blockDim.x) {
        uint4 v = ((const uint4*)hnew)[i];
        int j0 = (i * 8) % 96;
        uint u[4] = {v.x, v.y, v.z, v.w};
        uint o[4];
#pragma unroll
        for (int k = 0; k < 4; ++k) {
            int j = j0 + 2 * k;
            float f0 = b2f((ushort)u[k])        * sc[j]     + sh[j];
            float f1 = b2f((ushort)(u[k] >> 16)) * sc[j + 1] + sh[j + 1];
            o[k] = pack2(f0 > 0.f ? f0 : 0.f, f1 > 0.f ? f1 : 0.f);
        }
        ((uint4*)h)[i] = make_uint4(o[0], o[1], o[2], o[3]);
    }
}

// ---------------- central-node MLP head ----------------
__global__ __launch_bounds__(128) void k_mlp(const ushort* __restrict__ h,
        const int* __restrict__ cidx, const float* __restrict__ W1,
        const float* __restrict__ b1, const float* __restrict__ W2,
        const float* __restrict__ b2, float* __restrict__ out) {
    __shared__ float hid[96];
    __shared__ float red[128];
    const int c = blockIdx.x;
    const int node = cidx[c];
    const int tid = threadIdx.x;
    if (tid < 96) {
        float a = 0.f;
        const ushort* hr = h + (size_t)node * 96;
        for (int k = 0; k < 96; ++k) a += b2f(hr[k]) * W1[k * 96 + tid];
        hid[tid] = fmaxf(a + b1[tid], 0.f);
    }
    __syncthreads();
    red[tid] = (tid < 96) ? hid[tid] * W2[tid] : 0.f;
    __syncthreads();
    for (int off = 64; off > 0; off >>= 1) {
        if (tid < off) red[tid] += red[tid + off];
        __syncthreads();
    }
    if (tid == 0) out[c] = red[0] + b2[0];
}

extern "C" void kernel_launch(void* const* d_in, const int* in_sizes, int n_in,
                              void* d_out, int out_size, void* d_ws, size_t ws_size,
                              hipStream_t stream) {
    const float* x        = (const float*)d_in[0];
    const int*   ei       = (const int*)d_in[1];
    const int*   cidx     = (const int*)d_in[3];
    const float* W_emb    = (const float*)d_in[4];
    const float* b_emb    = (const float*)d_in[5];
    const float* conv_wl  = (const float*)d_in[6];
    const float* conv_bl  = (const float*)d_in[7];
    const float* conv_wr  = (const float*)d_in[8];
    const float* bn_gamma = (const float*)d_in[9];
    const float* bn_beta  = (const float*)d_in[10];
    const float* W1       = (const float*)d_in[11];
    const float* b1       = (const float*)d_in[12];
    const float* W2       = (const float*)d_in[13];
    const float* b2       = (const float*)d_in[14];
    float* out = (float*)d_out;

    char* ws = (char*)d_ws;
    size_t off = 0;
    auto alloc = [&](size_t bytes) -> void* {
        void* p = ws + off;
        off = (off + bytes + 255) & ~(size_t)255;
        return p;
    };
    ushort* h    = (ushort*)alloc((size_t)NN * 96 * 2);
    ushort* agg  = (ushort*)alloc((size_t)NN * 96 * 2);
    ushort* hnew = (ushort*)alloc((size_t)NN * 96 * 2);
    int*   hist  = (int*)alloc((size_t)NN * 4);
    int*   rp    = (int*)alloc((size_t)(NN + 1) * 4);
    int*   curs  = (int*)alloc((size_t)NN * 4);
    int*   col   = (int*)alloc((size_t)NE * 4);
    int*   bsum  = (int*)alloc(128 * 4);
    int*   boff  = (int*)alloc(128 * 4);
    float* stats = (float*)alloc((size_t)NL * 192 * 4);
    ushort* Bfe  = (ushort*)alloc((size_t)2 * 6 * 64 * 8 * 2);
    ushort* Bfl  = (ushort*)alloc((size_t)NL * 6 * 6 * 64 * 8 * 2);
    (void)ws_size; (void)in_sizes; (void)n_in; (void)out_size;

    const int NB = (NN + 1023) / 1024;

    hipMemsetAsync(hist, 0, (size_t)NN * 4, stream);
    hipMemsetAsync(stats, 0, (size_t)NL * 192 * 4, stream);

    k_prep<<<3, 256, 0, stream>>>(W_emb, nullptr, Bfe, 2);
    for (int l = 0; l < NL; ++l)
        k_prep<<<9, 256, 0, stream>>>(conv_wl + (size_t)l * 96 * 96,
                                      conv_wr + (size_t)l * 96 * 96,
                                      Bfl + (size_t)l * 18432, 6);

    k_embed<<<(NN + 127) / 128, 256, 0, stream>>>(x, Bfe, b_emb, h);
    k_hist<<<(NE + 255) / 256, 256, 0, stream>>>(ei, hist);
    k_scan1<<<NB, 1024, 0, stream>>>(hist, rp, bsum);
    k_scan2<<<1, 128, 0, stream>>>(bsum, boff);
    k_scan3<<<NB, 1024, 0, stream>>>(rp, boff);
    hipMemcpyAsync(curs, rp, (size_t)NN * 4, hipMemcpyDeviceToDevice, stream);
    k_fill<<<(NE + 255) / 256, 256, 0, stream>>>(ei, curs, col);

    for (int l = 0; l < NL; ++l) {
        k_agg<<<(NN + 15) / 16, 256, 0, stream>>>(h, rp, col, agg);
        k_gemm<<<(NN + 127) / 128, 256, 0, stream>>>(agg, h,
            Bfl + (size_t)l * 18432, conv_bl + (size_t)l * 96, hnew,
            stats + (size_t)l * 192);
        k_norm<<<2048, 256, 0, stream>>>(hnew, stats + (size_t)l * 192,
            bn_gamma + (size_t)l * 96, bn_beta + (size_t)l * 96, h);
    }
    k_mlp<<<NC, 128, 0, stream>>>(h, cidx, W1, b1, W2, b2, out);
}

// Round 4
// 322.347 us; speedup vs baseline: 3.5883x; 1.1290x over previous
//
#include <hip/hip_runtime.h>

#define NN 100000
#define NE 800000
#define IND 64
#define HID 96
#define NL 3
#define NC 512
#define BN_EPS 1e-5f

typedef __attribute__((ext_vector_type(8))) short bf16x8;
typedef __attribute__((ext_vector_type(4))) float f32x4;

static __device__ __forceinline__ float b2f(ushort u) {
    union { uint i; float f; } v; v.i = ((uint)u) << 16; return v.f;
}
static __device__ __forceinline__ ushort f2b(float f) {
    union { float f; uint i; } v; v.f = f;
    uint r = v.i + 0x7FFFu + ((v.i >> 16) & 1u);
    return (ushort)(r >> 16);
}
static __device__ __forceinline__ uint pack2(float a, float b) {
    return (uint)f2b(a) | ((uint)f2b(b) << 16);
}

// ---- weight prep: fp32 [K][96] (srcA rows 0..95, srcB rows 96..191) ->
// frag-ordered bf16: dst[((kt*6+ct)*64+lane)*8+j] = W[kt*32+(lane>>4)*8+j][ct*16+(lane&15)]
__global__ void k_prep(const float* __restrict__ srcA, const float* __restrict__ srcB,
                       ushort* __restrict__ dst, int ktiles) {
    int t = blockIdx.x * blockDim.x + threadIdx.x;
    int total = ktiles * 6 * 64;
    if (t >= total) return;
    int lane = t & 63;
    int ct = (t >> 6) % 6;
    int kt = t / (6 * 64);
    int k0 = kt * 32 + (lane >> 4) * 8;
    int col = ct * 16 + (lane & 15);
    ushort tmp[8];
#pragma unroll
    for (int j = 0; j < 8; ++j) {
        int k = k0 + j;
        const float* src = (srcB == nullptr || k < 96) ? srcA : srcB;
        int kk = (srcB == nullptr || k < 96) ? k : k - 96;
        tmp[j] = f2b(src[kk * HID + col]);
    }
    uint* od = (uint*)(dst + (size_t)t * 8);
    od[0] = (uint)tmp[0] | ((uint)tmp[1] << 16);
    od[1] = (uint)tmp[2] | ((uint)tmp[3] << 16);
    od[2] = (uint)tmp[4] | ((uint)tmp[5] << 16);
    od[3] = (uint)tmp[6] | ((uint)tmp[7] << 16);
}

// ---- embedding: h = relu(x @ W_emb + b_emb), bf16 out, MFMA ----
__global__ __launch_bounds__(256, 4) void k_embed(const float* __restrict__ x,
        const ushort* __restrict__ Bf, const float* __restrict__ bias,
        ushort* __restrict__ h) {
    __shared__ __align__(16) char smem[24576];
    ushort* sB = (ushort*)smem;          // 2*6*64*8 = 6144 ushorts (12288 B)
    ushort* sT = (ushort*)smem;          // reused after sync: 128*96 (24576 B)
    const int tid = threadIdx.x;
    for (int i = tid; i < 768; i += 256) ((uint4*)sB)[i] = ((const uint4*)Bf)[i];
    __syncthreads();
    const int wave = tid >> 6, lane = tid & 63;
    const int rowb = wave * 32;
    const int row0 = blockIdx.x * 128 + rowb;
    const int kof = (lane >> 4) * 8;
    f32x4 acc[2][6];
#pragma unroll
    for (int t = 0; t < 2; ++t)
#pragma unroll
        for (int c = 0; c < 6; ++c) acc[t][c] = (f32x4){0.f, 0.f, 0.f, 0.f};
#pragma unroll
    for (int kt = 0; kt < 2; ++kt) {
        int kk = kt * 32 + kof;
        bf16x8 a[2];
#pragma unroll
        for (int t = 0; t < 2; ++t) {
            int r = row0 + t * 16 + (lane & 15);
            if (r >= NN) r = NN - 1;
            const float* src = x + (size_t)r * IND + kk;
            float4 f0 = *(const float4*)src;
            float4 f1 = *(const float4*)(src + 4);
            a[t][0] = (short)f2b(f0.x); a[t][1] = (short)f2b(f0.y);
            a[t][2] = (short)f2b(f0.z); a[t][3] = (short)f2b(f0.w);
            a[t][4] = (short)f2b(f1.x); a[t][5] = (short)f2b(f1.y);
            a[t][6] = (short)f2b(f1.z); a[t][7] = (short)f2b(f1.w);
        }
#pragma unroll
        for (int ct = 0; ct < 6; ++ct) {
            bf16x8 bb = *(const bf16x8*)&sB[((kt * 6 + ct) * 64 + lane) * 8];
            acc[0][ct] = __builtin_amdgcn_mfma_f32_16x16x32_bf16(a[0], bb, acc[0][ct], 0, 0, 0);
            acc[1][ct] = __builtin_amdgcn_mfma_f32_16x16x32_bf16(a[1], bb, acc[1][ct], 0, 0, 0);
        }
    }
    __syncthreads();   // done reading sB
#pragma unroll
    for (int t = 0; t < 2; ++t)
#pragma unroll
        for (int ct = 0; ct < 6; ++ct) {
            int col = ct * 16 + (lane & 15);
            float bv = bias[col];
#pragma unroll
            for (int i = 0; i < 4; ++i) {
                int rb = rowb + t * 16 + (lane >> 4) * 4 + i;
                float v = acc[t][ct][i] + bv;
                sT[rb * HID + col] = f2b(v > 0.f ? v : 0.f);
            }
        }
    __syncthreads();
    for (int i = tid; i < 1536; i += 256) {      // 128 rows * 12 uint4
        int r = i / 12;
        int g = blockIdx.x * 128 + r;
        if (g < NN) ((uint4*)(h + (size_t)g * HID))[i % 12] = ((uint4*)sT)[i];
    }
}

// ---------------- CSR build ----------------
__global__ void k_hist(const int* __restrict__ ei, int* __restrict__ hist) {
    int e = blockIdx.x * blockDim.x + threadIdx.x;
    if (e < NE) atomicAdd(&hist[ei[NE + e]], 1);
}

__global__ __launch_bounds__(1024) void k_scan1(const int* __restrict__ hist,
        int* __restrict__ rp, int* __restrict__ bsum) {
    __shared__ int sd[1024];
    const int tid = threadIdx.x;
    const int i = blockIdx.x * 1024 + tid;
    int v = (i < NN) ? hist[i] : 0;
    sd[tid] = v;
    __syncthreads();
    for (int off = 1; off < 1024; off <<= 1) {
        int t = (tid >= off) ? sd[tid - off] : 0;
        __syncthreads();
        sd[tid] += t;
        __syncthreads();
    }
    if (i < NN) rp[i] = sd[tid] - v;
    if (tid == 1023) bsum[blockIdx.x] = sd[1023];
}

__global__ __launch_bounds__(128) void k_scan2(const int* __restrict__ bsum,
                                               int* __restrict__ boff) {
    __shared__ int sd[128];
    const int tid = threadIdx.x;
    const int NB = (NN + 1023) / 1024;
    int v = (tid < NB) ? bsum[tid] : 0;
    sd[tid] = v;
    __syncthreads();
    for (int off = 1; off < 128; off <<= 1) {
        int t = (tid >= off) ? sd[tid - off] : 0;
        __syncthreads();
        sd[tid] += t;
        __syncthreads();
    }
    if (tid < NB) boff[tid] = sd[tid] - v;
}

__global__ __launch_bounds__(1024) void k_scan3(int* __restrict__ rp,
        const int* __restrict__ boff) {
    const int i = blockIdx.x * 1024 + threadIdx.x;
    if (i < NN) rp[i] += boff[blockIdx.x];
    if (i == 0) rp[NN] = NE;
}

__global__ void k_fill(const int* __restrict__ ei, int* __restrict__ cursor,
                       int* __restrict__ col) {
    int e = blockIdx.x * blockDim.x + threadIdx.x;
    if (e < NE) {
        int d = ei[NE + e];
        int pos = atomicAdd(&cursor[d], 1);
        col[pos] = ei[e];
    }
}

// ---- mean aggregation, BN(prev layer)+ReLU fused on gather, 4-edge unroll ----
__global__ __launch_bounds__(256) void k_agg(const ushort* __restrict__ pre,
        const int* __restrict__ rp, const int* __restrict__ col,
        const float* __restrict__ stats, const float* __restrict__ gamma,
        const float* __restrict__ beta, ushort* __restrict__ agg) {
    __shared__ float sc[96], sh[96];
    const int tid = threadIdx.x;
    if (tid < 96) {
        float scv = 1.f, shv = 0.f;
        if (stats) {
            float mean = stats[tid] * (1.f / NN);
            float var  = stats[96 + tid] * (1.f / NN) - mean * mean;
            float s = gamma[tid] * rsqrtf(var + BN_EPS);
            scv = s; shv = beta[tid] - mean * s;
        }
        sc[tid] = scv; sh[tid] = shv;
    }
    __syncthreads();
    const int lane = tid & 15;
    const int n = blockIdx.x * 16 + (tid >> 4);
    if (n >= NN) return;
    const float s0a = sc[2*lane],      h0a = sh[2*lane];
    const float s0b = sc[2*lane + 1],  h0b = sh[2*lane + 1];
    const float s1a = sc[2*lane + 32], h1a = sh[2*lane + 32];
    const float s1b = sc[2*lane + 33], h1b = sh[2*lane + 33];
    const float s2a = sc[2*lane + 64], h2a = sh[2*lane + 64];
    const float s2b = sc[2*lane + 65], h2b = sh[2*lane + 65];
    const int e0 = rp[n], e1 = rp[n + 1];
    float a0 = 0.f, a1 = 0.f, a2 = 0.f, a3 = 0.f, a4 = 0.f, a5 = 0.f;
    const uint* hu = (const uint*)pre;
    int e = e0;
    for (; e + 4 <= e1; e += 4) {
        uint u[4][3];
#pragma unroll
        for (int i = 0; i < 4; ++i) {
            const uint* r = hu + (size_t)col[e + i] * 48 + lane;
            u[i][0] = r[0]; u[i][1] = r[16]; u[i][2] = r[32];
        }
#pragma unroll
        for (int i = 0; i < 4; ++i) {
            a0 += fmaxf(b2f((ushort)u[i][0])         * s0a + h0a, 0.f);
            a1 += fmaxf(b2f((ushort)(u[i][0] >> 16)) * s0b + h0b, 0.f);
            a2 += fmaxf(b2f((ushort)u[i][1])         * s1a + h1a, 0.f);
            a3 += fmaxf(b2f((ushort)(u[i][1] >> 16)) * s1b + h1b, 0.f);
            a4 += fmaxf(b2f((ushort)u[i][2])         * s2a + h2a, 0.f);
            a5 += fmaxf(b2f((ushort)(u[i][2] >> 16)) * s2b + h2b, 0.f);
        }
    }
    for (; e < e1; ++e) {
        const uint* r = hu + (size_t)col[e] * 48 + lane;
        uint u0 = r[0], u1 = r[16], u2 = r[32];
        a0 += fmaxf(b2f((ushort)u0)         * s0a + h0a, 0.f);
        a1 += fmaxf(b2f((ushort)(u0 >> 16)) * s0b + h0b, 0.f);
        a2 += fmaxf(b2f((ushort)u1)         * s1a + h1a, 0.f);
        a3 += fmaxf(b2f((ushort)(u1 >> 16)) * s1b + h1b, 0.f);
        a4 += fmaxf(b2f((ushort)u2)         * s2a + h2a, 0.f);
        a5 += fmaxf(b2f((ushort)(u2 >> 16)) * s2b + h2b, 0.f);
    }
    int d = e1 - e0; if (d < 1) d = 1;
    float inv = 1.0f / (float)d;
    uint* ar = (uint*)agg + (size_t)n * 48 + lane;
    ar[0]  = pack2(a0 * inv, a1 * inv);
    ar[16] = pack2(a2 * inv, a3 * inv);
    ar[32] = pack2(a4 * inv, a5 * inv);
}

// ---- layer GEMM: hnew = [agg | norm_prev(pre)] @ [[wl],[wr]] + bl, fused BN stats ----
__global__ __launch_bounds__(256, 4) void k_gemm(const ushort* __restrict__ aggb,
        const ushort* __restrict__ pre, const ushort* __restrict__ Bf,
        const float* __restrict__ bl, ushort* __restrict__ hnew,
        float* __restrict__ stats,
        const float* __restrict__ statsP, const float* __restrict__ gammaP,
        const float* __restrict__ betaP) {
    __shared__ __align__(16) char smem[40704];
    ushort* sB = (ushort*)smem;                    // 36864 B
    ushort* sT = (ushort*)smem;                    // reused after sync (24576 B)
    float*  sredS = (float*)(smem + 36864);        // 384 floats
    float*  sredQ = (float*)(smem + 38400);        // 384 floats
    float2* sscsh = (float2*)(smem + 39936);       // 96 float2
    const int tid = threadIdx.x;
    for (int i = tid; i < 2304; i += 256) ((uint4*)sB)[i] = ((const uint4*)Bf)[i];
    if (tid < 96) {
        float scv = 1.f, shv = 0.f;
        if (statsP) {
            float mean = statsP[tid] * (1.f / NN);
            float var  = statsP[96 + tid] * (1.f / NN) - mean * mean;
            float s = gammaP[tid] * rsqrtf(var + BN_EPS);
            scv = s; shv = betaP[tid] - mean * s;
        }
        sscsh[tid] = make_float2(scv, shv);
    }
    __syncthreads();
    const int wave = tid >> 6, lane = tid & 63;
    const int rowb = wave * 32;
    const int row0 = blockIdx.x * 128 + rowb;
    const int kof = (lane >> 4) * 8;
    f32x4 acc[2][6];
#pragma unroll
    for (int t = 0; t < 2; ++t)
#pragma unroll
        for (int c = 0; c < 6; ++c) acc[t][c] = (f32x4){0.f, 0.f, 0.f, 0.f};
#pragma unroll
    for (int kt = 0; kt < 6; ++kt) {
        bf16x8 a[2];
#pragma unroll
        for (int t = 0; t < 2; ++t) {
            int r = row0 + t * 16 + (lane & 15);
            if (r >= NN) r = NN - 1;
            if (kt < 3) {
                int kk = kt * 32 + kof;
                a[t] = *(const bf16x8*)(aggb + (size_t)r * HID + kk);
            } else {
                int kk = (kt - 3) * 32 + kof;
                bf16x8 raw = *(const bf16x8*)(pre + (size_t)r * HID + kk);
                union { bf16x8 h; uint u[4]; } pk;
#pragma unroll
                for (int j = 0; j < 4; ++j) {
                    float2 p0 = sscsh[kk + 2*j];
                    float2 p1 = sscsh[kk + 2*j + 1];
                    float v0 = fmaxf(b2f((ushort)raw[2*j])     * p0.x + p0.y, 0.f);
                    float v1 = fmaxf(b2f((ushort)raw[2*j + 1]) * p1.x + p1.y, 0.f);
                    pk.u[j] = pack2(v0, v1);
                }
                a[t] = pk.h;
            }
        }
#pragma unroll
        for (int ct = 0; ct < 6; ++ct) {
            bf16x8 bb = *(const bf16x8*)&sB[((kt * 6 + ct) * 64 + lane) * 8];
            acc[0][ct] = __builtin_amdgcn_mfma_f32_16x16x32_bf16(a[0], bb, acc[0][ct], 0, 0, 0);
            acc[1][ct] = __builtin_amdgcn_mfma_f32_16x16x32_bf16(a[1], bb, acc[1][ct], 0, 0, 0);
        }
    }
    __syncthreads();   // done reading sB
    float s[6], q[6];
#pragma unroll
    for (int c = 0; c < 6; ++c) { s[c] = 0.f; q[c] = 0.f; }
#pragma unroll
    for (int t = 0; t < 2; ++t)
#pragma unroll
        for (int ct = 0; ct < 6; ++ct) {
            int col = ct * 16 + (lane & 15);
            float bv = bl[col];
#pragma unroll
            for (int i = 0; i < 4; ++i) {
                int rb = rowb + t * 16 + (lane >> 4) * 4 + i;
                int g = blockIdx.x * 128 + rb;
                float v = acc[t][ct][i] + bv;
                if (g < NN) { s[ct] += v; q[ct] += v * v; }
                sT[rb * HID + col] = f2b(v);
            }
        }
#pragma unroll
    for (int c = 0; c < 6; ++c) {
        s[c] += __shfl_xor(s[c], 16); s[c] += __shfl_xor(s[c], 32);
        q[c] += __shfl_xor(q[c], 16); q[c] += __shfl_xor(q[c], 32);
    }
    if (lane < 16) {
#pragma unroll
        for (int c = 0; c < 6; ++c) {
            sredS[wave * 96 + c * 16 + lane] = s[c];
            sredQ[wave * 96 + c * 16 + lane] = q[c];
        }
    }
    __syncthreads();
    if (tid < 96) {
        float S = sredS[tid] + sredS[96 + tid] + sredS[192 + tid] + sredS[288 + tid];
        float Q = sredQ[tid] + sredQ[96 + tid] + sredQ[192 + tid] + sredQ[288 + tid];
        atomicAdd(&stats[tid], S);
        atomicAdd(&stats[96 + tid], Q);
    }
    for (int i = tid; i < 1536; i += 256) {
        int r = i / 12;
        int g = blockIdx.x * 128 + r;
        if (g < NN) ((uint4*)(hnew + (size_t)g * HID))[i % 12] = ((uint4*)sT)[i];
    }
}

// ---------------- central-node MLP head (final BN+ReLU fused) ----------------
__global__ __launch_bounds__(128) void k_mlp(const ushort* __restrict__ pre,
        const int* __restrict__ cidx, const float* __restrict__ stats,
        const float* __restrict__ gamma, const float* __restrict__ beta,
        const float* __restrict__ W1, const float* __restrict__ b1,
        const float* __restrict__ W2, const float* __restrict__ b2,
        float* __restrict__ out) {
    __shared__ float nh[96];
    __shared__ float hid[96];
    __shared__ float red[128];
    const int c = blockIdx.x;
    const int node = cidx[c];
    const int tid = threadIdx.x;
    if (tid < 96) {
        float mean = stats[tid] * (1.f / NN);
        float var  = stats[96 + tid] * (1.f / NN) - mean * mean;
        float s = gamma[tid] * rsqrtf(var + BN_EPS);
        float v = b2f(pre[(size_t)node * 96 + tid]) * s + (beta[tid] - mean * s);
        nh[tid] = fmaxf(v, 0.f);
    }
    __syncthreads();
    if (tid < 96) {
        float a = 0.f;
        for (int k = 0; k < 96; ++k) a += nh[k] * W1[k * 96 + tid];
        hid[tid] = fmaxf(a + b1[tid], 0.f);
    }
    __syncthreads();
    red[tid] = (tid < 96) ? hid[tid] * W2[tid] : 0.f;
    __syncthreads();
    for (int off = 64; off > 0; off >>= 1) {
        if (tid < off) red[tid] += red[tid + off];
        __syncthreads();
    }
    if (tid == 0) out[c] = red[0] + b2[0];
}

extern "C" void kernel_launch(void* const* d_in, const int* in_sizes, int n_in,
                              void* d_out, int out_size, void* d_ws, size_t ws_size,
                              hipStream_t stream) {
    const float* x        = (const float*)d_in[0];
    const int*   ei       = (const int*)d_in[1];
    const int*   cidx     = (const int*)d_in[3];
    const float* W_emb    = (const float*)d_in[4];
    const float* b_emb    = (const float*)d_in[5];
    const float* conv_wl  = (const float*)d_in[6];
    const float* conv_bl  = (const float*)d_in[7];
    const float* conv_wr  = (const float*)d_in[8];
    const float* bn_gamma = (const float*)d_in[9];
    const float* bn_beta  = (const float*)d_in[10];
    const float* W1       = (const float*)d_in[11];
    const float* b1       = (const float*)d_in[12];
    const float* W2       = (const float*)d_in[13];
    const float* b2       = (const float*)d_in[14];
    float* out = (float*)d_out;

    char* ws = (char*)d_ws;
    size_t off = 0;
    auto alloc = [&](size_t bytes) -> void* {
        void* p = ws + off;
        off = (off + bytes + 255) & ~(size_t)255;
        return p;
    };
    ushort* h    = (ushort*)alloc((size_t)NN * 96 * 2);
    ushort* hnew = (ushort*)alloc((size_t)NN * 96 * 2);
    ushort* agg  = (ushort*)alloc((size_t)NN * 96 * 2);
    int*   hist  = (int*)alloc((size_t)NN * 4);
    int*   rp    = (int*)alloc((size_t)(NN + 1) * 4);
    int*   curs  = (int*)alloc((size_t)NN * 4);
    int*   col   = (int*)alloc((size_t)NE * 4);
    int*   bsum  = (int*)alloc(128 * 4);
    int*   boff  = (int*)alloc(128 * 4);
    float* stats = (float*)alloc((size_t)NL * 192 * 4);
    ushort* Bfe  = (ushort*)alloc((size_t)2 * 6 * 64 * 8 * 2);
    ushort* Bfl  = (ushort*)alloc((size_t)NL * 6 * 6 * 64 * 8 * 2);
    (void)ws_size; (void)in_sizes; (void)n_in; (void)out_size;

    const int NB = (NN + 1023) / 1024;

    hipMemsetAsync(hist, 0, (size_t)NN * 4, stream);
    hipMemsetAsync(stats, 0, (size_t)NL * 192 * 4, stream);

    k_prep<<<3, 256, 0, stream>>>(W_emb, nullptr, Bfe, 2);
    for (int l = 0; l < NL; ++l)
        k_prep<<<9, 256, 0, stream>>>(conv_wl + (size_t)l * 96 * 96,
                                      conv_wr + (size_t)l * 96 * 96,
                                      Bfl + (size_t)l * 18432, 6);

    k_embed<<<(NN + 127) / 128, 256, 0, stream>>>(x, Bfe, b_emb, h);
    k_hist<<<(NE + 255) / 256, 256, 0, stream>>>(ei, hist);
    k_scan1<<<NB, 1024, 0, stream>>>(hist, rp, bsum);
    k_scan2<<<1, 128, 0, stream>>>(bsum, boff);
    k_scan3<<<NB, 1024, 0, stream>>>(rp, boff);
    hipMemcpyAsync(curs, rp, (size_t)NN * 4, hipMemcpyDeviceToDevice, stream);
    k_fill<<<(NE + 255) / 256, 256, 0, stream>>>(ei, curs, col);

    // ping-pong: src -> dst per layer
    const ushort* src = h;
    ushort* dst = hnew;
    for (int l = 0; l < NL; ++l) {
        const float* stP = (l == 0) ? nullptr : stats + (size_t)(l - 1) * 192;
        const float* gP  = (l == 0) ? nullptr : bn_gamma + (size_t)(l - 1) * 96;
        const float* bP  = (l == 0) ? nullptr : bn_beta + (size_t)(l - 1) * 96;
        k_agg<<<(NN + 15) / 16, 256, 0, stream>>>(src, rp, col, stP, gP, bP, agg);
        k_gemm<<<(NN + 127) / 128, 256, 0, stream>>>(agg, src,
            Bfl + (size_t)l * 18432, conv_bl + (size_t)l * 96, dst,
            stats + (size_t)l * 192, stP, gP, bP);
        const ushort* t = src; src = dst; dst = (ushort*)t;
    }
    k_mlp<<<NC, 128, 0, stream>>>(src, cidx, stats + (size_t)(NL - 1) * 192,
        bn_gamma + (size_t)(NL - 1) * 96, bn_beta + (size_t)(NL - 1) * 96,
        W1, b1, W2, b2, out);
}